// Round 17
// baseline (78.371 us; speedup 1.0000x reference)
//
#include <hip/hip_runtime.h>
#include <stdint.h>

// FMFMNeuron LIF scan, 4-phase; scanA = 2-way IN-THREAD ILP:
//  1) compress: 134MB f32 spikes -> 4MB 2-bit cur-codes [T/16][B] (nt loads)
//  2) scanA2: C=32 chunks; each thread runs TWO independent chains
//     (neuron b, chunk c) and (b, c+16), explicitly interleaved step-by-step
//     to fill dep-latency bubbles at COMPILE time (r15/r16: HW wave
//     interleaving recovered almost nothing; 63cy/step at 1 wave, 44 at 2).
//     768-step warmup from mem=0; chunks<6 virtually zero-padded (cur=0 steps
//     from (0,0) are exact identities) => uniform 56-word schedule; 128-step
//     body emits 1-bit spikes. 65536 threads = 256 blocks = 1 block/CU.
//  3) scanB: chain 32 chunks via bit-compare; mismatch -> recompute + patch
//     bits. Unconditionally exact.
//  4) expand: 2MB bits -> 67MB f32 at full occupancy (2048 blocks).
//
// Step math (absmax=0 rounds 1..16): spikes in {0,1} =>
//   cur in {0, w1, w2, fadd(w1,w2)} exactly; strict left-to-right:
//   m = fsub(fadd(fmul(0.95f,mem), cur), rst); spk = m>1.0f; rst' = spk.

#define T_STEPS 4096
#define B_NEUR  4096
#define NCHUNK  32
#define CH_W    8                      // code words per chunk body (128 steps)
#define WARM_W  48                     // warmup words (768 steps)
#define KG      (T_STEPS / 16)         // 256 code words per neuron
#define NWORDS  (T_STEPS / 32)         // 128 spike bit-words per neuron

typedef float f4v __attribute__((ext_vector_type(4)));

// ---- phase 1: compress spikes to 2-bit codes (nt float4 loads) -------------
__global__ __launch_bounds__(256) void fmfm_compress(
    const f4v*  __restrict__ sp4,      // [T][B/2] float4
    uint32_t*   __restrict__ codes)    // [T/16][B]
{
    const int tid = blockIdx.x * 256 + threadIdx.x;   // 0 .. 512K-1
    const int b2  = tid & (B_NEUR / 2 - 1);
    const int kg  = tid >> 11;                        // 0..255
    const f4v* p = sp4 + (size_t)kg * 16 * (B_NEUR / 2) + b2;
    uint32_t we = 0, wo = 0;
    #pragma unroll
    for (int i = 0; i < 16; ++i) {
        f4v s = __builtin_nontemporal_load(p + (size_t)i * (B_NEUR / 2));
        uint32_t ce = (s.x != 0.0f ? 1u : 0u) | (s.y != 0.0f ? 2u : 0u);
        uint32_t co = (s.z != 0.0f ? 1u : 0u) | (s.w != 0.0f ? 2u : 0u);
        we |= ce << (2 * i);
        wo |= co << (2 * i);
    }
    *reinterpret_cast<uint2*>(codes + (size_t)kg * B_NEUR + 2 * b2) =
        make_uint2(we, wo);
}

// ---- phase 2: dual-chain speculative scan -> spike bits --------------------
__global__ __launch_bounds__(256, 1) void fmfm_scanA2(
    const uint32_t* __restrict__ codes,    // [T/16][B]
    const float*    __restrict__ W,
    uint32_t*       __restrict__ bits_out, // [T/32][B]
    uint4*          __restrict__ spec)     // [C][B]
{
    __shared__ float2 lut2[16];

    const float w1  = W[0];
    const float w2  = W[1];
    const float w12 = __fadd_rn(w1, w2);

    if (threadIdx.x < 16) {
        uint32_t e = threadIdx.x;
        uint32_t q0 = e & 3u, q1 = (e >> 2) & 3u;
        float2 v;
        v.x = (q0 & 1u) ? ((q0 & 2u) ? w12 : w1) : ((q0 & 2u) ? w2 : 0.0f);
        v.y = (q1 & 1u) ? ((q1 & 2u) ? w12 : w1) : ((q1 & 2u) ? w2 : 0.0f);
        lut2[e] = v;
    }
    __syncthreads();

    const int tid = blockIdx.x * 256 + threadIdx.x;   // 0..65535
    const int b   = tid & (B_NEUR - 1);
    const int cpair = tid >> 12;                      // 0..15
    const int cA  = cpair;                            // chunk A
    const int cB  = cpair + 16;                       // chunk B
    const int wA0 = cA * CH_W - WARM_W;               // may be negative
    const int wB0 = cB * CH_W - WARM_W;               // >= 80
    const uint32_t* cptr = codes + b;

#define FA(V) (((wA0 + (V)) < 0) ? 0u                                     \
                : cptr[(size_t)(wA0 + (V)) * B_NEUR])
#define FB(V) cptr[(size_t)(wB0 + (V)) * B_NEUR]
#define DECODE2(WORD, D)                                                  \
    {                                                                     \
        _Pragma("unroll")                                                 \
        for (int _j = 0; _j < 8; ++_j)                                    \
            D[_j] = lut2[((WORD) >> (4 * _j)) & 0xFu];                    \
    }
#define STEPN_A(CUR)                                                      \
    {                                                                     \
        float _m = __fsub_rn(__fadd_rn(__fmul_rn(0.95f, memA), (CUR)),    \
                             rstA);                                       \
        rstA = (_m > 1.0f) ? 1.0f : 0.0f;                                 \
        memA = _m;                                                        \
    }
#define STEPN_B(CUR)                                                      \
    {                                                                     \
        float _m = __fsub_rn(__fadd_rn(__fmul_rn(0.95f, memB), (CUR)),    \
                             rstB);                                       \
        rstB = (_m > 1.0f) ? 1.0f : 0.0f;                                 \
        memB = _m;                                                        \
    }
#define STEPB_A(CUR, POS)                                                 \
    {                                                                     \
        float _m = __fsub_rn(__fadd_rn(__fmul_rn(0.95f, memA), (CUR)),    \
                             rstA);                                       \
        uint32_t _sb = (_m > 1.0f) ? 1u : 0u;                             \
        bitsA |= _sb << (POS);                                            \
        rstA = _sb ? 1.0f : 0.0f;                                         \
        memA = _m;                                                        \
    }
#define STEPB_B(CUR, POS)                                                 \
    {                                                                     \
        float _m = __fsub_rn(__fadd_rn(__fmul_rn(0.95f, memB), (CUR)),    \
                             rstB);                                       \
        uint32_t _sb = (_m > 1.0f) ? 1u : 0u;                             \
        bitsB |= _sb << (POS);                                            \
        rstB = _sb ? 1.0f : 0.0f;                                         \
        memB = _m;                                                        \
    }
// interleaved 16-step word for both chains
#define CH2N(DA, DB)                                                      \
    {                                                                     \
        _Pragma("unroll")                                                 \
        for (int _j = 0; _j < 8; ++_j) {                                  \
            STEPN_A(DA[_j].x) STEPN_B(DB[_j].x)                           \
            STEPN_A(DA[_j].y) STEPN_B(DB[_j].y)                           \
        }                                                                 \
    }
#define CH2B(DA, DB, HALF)                                                \
    {                                                                     \
        _Pragma("unroll")                                                 \
        for (int _j = 0; _j < 8; ++_j) {                                  \
            STEPB_A(DA[_j].x, ((HALF) << 4) + 2 * _j)                     \
            STEPB_B(DB[_j].x, ((HALF) << 4) + 2 * _j)                     \
            STEPB_A(DA[_j].y, ((HALF) << 4) + 2 * _j + 1)                 \
            STEPB_B(DB[_j].y, ((HALF) << 4) + 2 * _j + 1)                 \
        }                                                                 \
    }

    // prologue: words v=0..7 per chain; decode v=0
    uint32_t a1 = FA(1), a2 = FA(2), a3 = FA(3), a4 = FA(4),
             a5 = FA(5), a6 = FA(6), a7 = FA(7);
    uint32_t b1 = FB(1), b2 = FB(2), b3 = FB(3), b4 = FB(4),
             b5 = FB(5), b6 = FB(6), b7 = FB(7);
    float2 dA0[8], dA1[8], dB0[8], dB1[8];
    {
        uint32_t wa0v = FA(0), wb0v = FB(0);
        DECODE2(wa0v, dA0)
        DECODE2(wb0v, dB0)
    }

    float memA = 0.0f, rstA = 0.0f, memB = 0.0f, rstB = 0.0f;

    // warmup: 6 groups x 8 words (48 words = 768 steps per chain)
    for (int g = 0; g < WARM_W; g += 8) {
        uint32_t tA0 = FA(g + 8),  tA1 = FA(g + 9),  tA2 = FA(g + 10),
                 tA3 = FA(g + 11), tA4 = FA(g + 12), tA5 = FA(g + 13),
                 tA6 = FA(g + 14), tA7 = FA(g + 15);
        uint32_t tB0 = FB(g + 8),  tB1 = FB(g + 9),  tB2 = FB(g + 10),
                 tB3 = FB(g + 11), tB4 = FB(g + 12), tB5 = FB(g + 13),
                 tB6 = FB(g + 14), tB7 = FB(g + 15);
        DECODE2(a1, dA1) DECODE2(b1, dB1) CH2N(dA0, dB0)
        DECODE2(a2, dA0) DECODE2(b2, dB0) CH2N(dA1, dB1)
        DECODE2(a3, dA1) DECODE2(b3, dB1) CH2N(dA0, dB0)
        DECODE2(a4, dA0) DECODE2(b4, dB0) CH2N(dA1, dB1)
        DECODE2(a5, dA1) DECODE2(b5, dB1) CH2N(dA0, dB0)
        DECODE2(a6, dA0) DECODE2(b6, dB0) CH2N(dA1, dB1)
        DECODE2(a7, dA1) DECODE2(b7, dB1) CH2N(dA0, dB0)
        DECODE2(tA0, dA0) DECODE2(tB0, dB0) CH2N(dA1, dB1)
        a1 = tA1; a2 = tA2; a3 = tA3; a4 = tA4; a5 = tA5; a6 = tA6; a7 = tA7;
        b1 = tB1; b2 = tB2; b3 = tB3; b4 = tB4; b5 = tB5; b6 = tB6; b7 = tB7;
    }

    const float smA = memA, srA = rstA, smB = memB, srB = rstB;

    // body: 8 words (128 steps) per chain; dA0/dB0 hold word v=48
    uint32_t bitsA = 0, bitsB = 0;
#define STBA(I) bits_out[(size_t)(cA * 4 + (I)) * B_NEUR + b] = bitsA; bitsA = 0;
#define STBB(I) bits_out[(size_t)(cB * 4 + (I)) * B_NEUR + b] = bitsB; bitsB = 0;
    DECODE2(a1, dA1) DECODE2(b1, dB1) CH2B(dA0, dB0, 0)
    DECODE2(a2, dA0) DECODE2(b2, dB0) CH2B(dA1, dB1, 1) STBA(0) STBB(0)
    DECODE2(a3, dA1) DECODE2(b3, dB1) CH2B(dA0, dB0, 0)
    DECODE2(a4, dA0) DECODE2(b4, dB0) CH2B(dA1, dB1, 1) STBA(1) STBB(1)
    DECODE2(a5, dA1) DECODE2(b5, dB1) CH2B(dA0, dB0, 0)
    DECODE2(a6, dA0) DECODE2(b6, dB0) CH2B(dA1, dB1, 1) STBA(2) STBB(2)
    DECODE2(a7, dA1) DECODE2(b7, dB1) CH2B(dA0, dB0, 0)
                                      CH2B(dA1, dB1, 1) STBA(3) STBB(3)

    uint4 svA, svB;
    svA.x = __float_as_uint(smA); svA.y = (srA != 0.0f) ? 1u : 0u;
    svA.z = __float_as_uint(memA); svA.w = (rstA != 0.0f) ? 1u : 0u;
    svB.x = __float_as_uint(smB); svB.y = (srB != 0.0f) ? 1u : 0u;
    svB.z = __float_as_uint(memB); svB.w = (rstB != 0.0f) ? 1u : 0u;
    spec[(size_t)cA * B_NEUR + b] = svA;
    spec[(size_t)cB * B_NEUR + b] = svB;

#undef FA
#undef FB
#undef DECODE2
#undef STEPN_A
#undef STEPN_B
#undef STEPB_A
#undef STEPB_B
#undef CH2N
#undef CH2B
#undef STBA
#undef STBB
}

// ---- phase 3: exact chaining / verification, patches bits ------------------
__global__ __launch_bounds__(64) void fmfm_scanB(
    const uint32_t* __restrict__ codes,
    const float*    __restrict__ W,
    uint32_t*       __restrict__ bits_out,
    const uint4*    __restrict__ spec)
{
    const int b = blockIdx.x * 64 + threadIdx.x;
    const float w1  = W[0];
    const float w2  = W[1];
    const float w12 = __fadd_rn(w1, w2);

    float mem = 0.0f, rst = 0.0f;
    uint4 sn = spec[b];
    for (int c = 0; c < NCHUNK; ++c) {
        uint4 s = sn;
        if (c + 1 < NCHUNK) sn = spec[(size_t)(c + 1) * B_NEUR + b];
        bool ok = (s.x == __float_as_uint(mem)) &&
                  ((s.y != 0u) == (rst != 0.0f));
        if (ok) {
            mem = __uint_as_float(s.z);
            rst = s.w ? 1.0f : 0.0f;
        } else {
            // rare: recompute chunk c exactly from true state, patch bits
            uint32_t bits = 0;
            for (int wi = 0; wi < CH_W; ++wi) {
                uint32_t w = codes[(size_t)(c * CH_W + wi) * B_NEUR + b];
                #pragma unroll
                for (int j = 0; j < 16; ++j) {
                    uint32_t cc = (w >> (2 * j)) & 3u;
                    float cur = (cc & 1u) ? ((cc & 2u) ? w12 : w1)
                                          : ((cc & 2u) ? w2 : 0.0f);
                    float m = __fsub_rn(__fadd_rn(__fmul_rn(0.95f, mem), cur),
                                        rst);
                    uint32_t sb = (m > 1.0f) ? 1u : 0u;
                    bits |= sb << (((wi & 1) << 4) + j);
                    rst = sb ? 1.0f : 0.0f;
                    mem = m;
                }
                if (wi & 1) {
                    bits_out[(size_t)((c * CH_W + wi) >> 1) * B_NEUR + b] = bits;
                    bits = 0;
                }
            }
        }
    }
}

// ---- phase 4: expand bits -> f32, full occupancy ---------------------------
__global__ __launch_bounds__(256) void fmfm_expand(
    const uint32_t* __restrict__ bits,  // [T/32][B]
    float*          __restrict__ out)   // [T][B]
{
    const int tid = blockIdx.x * 256 + threadIdx.x;  // 0..524287
    const int b4  = tid & 1023;                      // neuron quad
    const int w   = (tid >> 10) & 127;               // bit-word row
    const int q   = tid >> 17;                       // row octet 0..3
    const uint4 bw = *reinterpret_cast<const uint4*>(
        bits + (size_t)w * B_NEUR + (size_t)b4 * 4);
    float* qp = out + ((size_t)w * 32 + q * 8) * B_NEUR + (size_t)b4 * 4;
    #pragma unroll
    for (int r = 0; r < 8; ++r) {
        const int tp = q * 8 + r;
        f4v v;
        v.x = ((bw.x >> tp) & 1u) ? 1.0f : 0.0f;
        v.y = ((bw.y >> tp) & 1u) ? 1.0f : 0.0f;
        v.z = ((bw.z >> tp) & 1u) ? 1.0f : 0.0f;
        v.w = ((bw.w >> tp) & 1u) ? 1.0f : 0.0f;
        *reinterpret_cast<f4v*>(qp + (size_t)r * B_NEUR) = v;
    }
}

// ---- fallback: round-1 proven fused kernel (if ws too small) ---------------
__global__ __launch_bounds__(64) void fmfm_scan_fused(
    const float2* __restrict__ sp, const float* __restrict__ W,
    float* __restrict__ out)
{
    const int b = blockIdx.x * 64 + threadIdx.x;
    const float w1 = W[0];
    const float w2 = W[1];
    const float2* p = sp + b;
    float* q = out + b;
    float mem = 0.0f, rst = 0.0f;
    #pragma unroll 8
    for (int t = 0; t < T_STEPS; ++t) {
        float2 s = p[(size_t)t * B_NEUR];
        float cur = __fadd_rn(__fmul_rn(s.x, w1), __fmul_rn(s.y, w2));
        float m = __fsub_rn(__fadd_rn(__fmul_rn(0.95f, mem), cur), rst);
        float spk = (m > 1.0f) ? 1.0f : 0.0f;
        q[(size_t)t * B_NEUR] = spk;
        mem = m;
        rst = spk;
    }
}

extern "C" void kernel_launch(void* const* d_in, const int* in_sizes, int n_in,
                              void* d_out, int out_size, void* d_ws, size_t ws_size,
                              hipStream_t stream) {
    const f4v*   sp4 = (const f4v*)d_in[0];
    const float* W   = (const float*)d_in[1];
    float*       out = (float*)d_out;

    const size_t codes_bytes = (size_t)KG * B_NEUR * 4;          // 4MB
    const size_t bits_bytes  = (size_t)NWORDS * B_NEUR * 4;      // 2MB
    const size_t spec_bytes  = (size_t)NCHUNK * B_NEUR * 16;     // 2MB
    if (ws_size < codes_bytes + bits_bytes + spec_bytes) {
        fmfm_scan_fused<<<dim3(B_NEUR / 64), dim3(64), 0, stream>>>(
            (const float2*)d_in[0], W, out);
        return;
    }
    uint32_t* codes = (uint32_t*)d_ws;
    uint32_t* bits  = (uint32_t*)((char*)d_ws + codes_bytes);
    uint4*    spec  = (uint4*)((char*)d_ws + codes_bytes + bits_bytes);

    fmfm_compress<<<dim3(KG * (B_NEUR / 2) / 256), dim3(256), 0, stream>>>(sp4, codes);
    // dual-chain: 16 chunk-pairs x 4096 neurons = 65536 threads = 256 blocks
    fmfm_scanA2<<<dim3(256), dim3(256), 0, stream>>>(codes, W, bits, spec);
    fmfm_scanB<<<dim3(B_NEUR / 64), dim3(64), 0, stream>>>(codes, W, bits, spec);
    // 4 threads per 32-row bit-word: 128 * 1024 * 4 / 256 = 2048 blocks
    fmfm_expand<<<dim3(NWORDS * (B_NEUR / 4) * 4 / 256), dim3(256), 0, stream>>>(bits, out);
}